// Round 5
// baseline (3268.504 us; speedup 1.0000x reference)
//
#include <hip/hip_runtime.h>
#include <hip/hip_bf16.h>

#define N_NODES 50000
#define N_EDGES 600000
#define DD 128
#define N_LAYERS 6
#define SCAN_BLOCKS 196   // ceil(50000/256)
#define AGG_STRIDE 132    // f32 row stride for agg accumulator

typedef __attribute__((ext_vector_type(8))) short bf16x8;
typedef __attribute__((ext_vector_type(4))) float floatx4;

__device__ __forceinline__ void ldsdma16(const void* g, void* l) {
    __builtin_amdgcn_global_load_lds(
        (const __attribute__((address_space(1))) char*)g,
        (__attribute__((address_space(3))) char*)l, 16, 0, 0);
}

__device__ __forceinline__ unsigned short f2b(float f) {
    unsigned u = __float_as_uint(f);
    unsigned r = (u + 0x7FFFu + ((u >> 16) & 1u)) >> 16;
    return (unsigned short)r;
}

// ---------------- CSR build ----------------

__global__ void zero_counts(int* __restrict__ deg, int* __restrict__ cursor) {
    int i = blockIdx.x * blockDim.x + threadIdx.x;
    if (i < N_NODES) { deg[i] = 0; cursor[i] = 0; }
}

__global__ void count_deg(const int* __restrict__ dst, int* __restrict__ deg) {
    int e = blockIdx.x * blockDim.x + threadIdx.x;
    if (e < N_EDGES) atomicAdd(&deg[dst[e]], 1);
}

__global__ void block_sums(const int* __restrict__ deg, int* __restrict__ bsum) {
    __shared__ int s[256];
    int tid = threadIdx.x;
    int i = blockIdx.x * 256 + tid;
    int v = (i < N_NODES) ? deg[i] : 0;
    s[tid] = v;
    __syncthreads();
    #pragma unroll
    for (int off = 128; off > 0; off >>= 1) {
        if (tid < off) s[tid] += s[tid + off];
        __syncthreads();
    }
    if (tid == 0) bsum[blockIdx.x] = s[0];
}

__global__ void scan_bsums(int* __restrict__ bsum, int* __restrict__ offsets) {
    __shared__ int s[256];
    int tid = threadIdx.x;
    int v = (tid < SCAN_BLOCKS) ? bsum[tid] : 0;
    s[tid] = v;
    __syncthreads();
    for (int off = 1; off < 256; off <<= 1) {
        int t = (tid >= off) ? s[tid - off] : 0;
        __syncthreads();
        s[tid] += t;
        __syncthreads();
    }
    if (tid < SCAN_BLOCKS) bsum[tid] = s[tid] - v;   // exclusive
    if (tid == 0) offsets[N_NODES] = N_EDGES;
}

__global__ void write_offsets(const int* __restrict__ deg, const int* __restrict__ bsum,
                              int* __restrict__ offsets, float* __restrict__ deg_inv) {
    __shared__ int s[256];
    int tid = threadIdx.x;
    int i = blockIdx.x * 256 + tid;
    int v = (i < N_NODES) ? deg[i] : 0;
    s[tid] = v;
    __syncthreads();
    for (int off = 1; off < 256; off <<= 1) {
        int t = (tid >= off) ? s[tid - off] : 0;
        __syncthreads();
        s[tid] += t;
        __syncthreads();
    }
    if (i < N_NODES) {
        offsets[i] = bsum[blockIdx.x] + s[tid] - v;
        deg_inv[i] = 1.0f / (float)(v > 1 ? v : 1);
    }
}

__global__ void fill_csr(const int* __restrict__ src, const int* __restrict__ dst,
                         const int* __restrict__ offsets, int* __restrict__ cursor,
                         int* __restrict__ csr_src, int* __restrict__ csr_dst) {
    int e = blockIdx.x * blockDim.x + threadIdx.x;
    if (e < N_EDGES) {
        int d = dst[e];
        int p = atomicAdd(&cursor[d], 1);
        int slot = offsets[d] + p;
        csr_src[slot] = src[e];
        csr_dst[slot] = d;
    }
}

// ---------------- dtype prep ----------------

__global__ void x_to_bf16(const float* __restrict__ x, unsigned short* __restrict__ hx) {
    int idx = blockIdx.x * blockDim.x + threadIdx.x;
    int b = idx * 4;
    float4 v = *(const float4*)(x + b);
    ushort4 o;
    o.x = f2b(v.x); o.y = f2b(v.y); o.z = f2b(v.z); o.w = f2b(v.w);
    *(ushort4*)(hx + b) = o;
}

// WT2[l][n][k2]: k2<128 -> Wl[l][k2][n], else Wr[l][k2-128][n]   (bf16)
__global__ void prep_weights(const float* __restrict__ Wl, const float* __restrict__ Wr,
                             unsigned short* __restrict__ WT2) {
    int idx = blockIdx.x * blockDim.x + threadIdx.x;  // 6*128*256
    int l   = idx >> 15;
    int rem = idx & 32767;
    int n   = rem >> 8;
    int k2  = rem & 255;
    const float* W = (k2 < 128 ? Wl : Wr) + (size_t)l * DD * DD + (size_t)(k2 & 127) * DD + n;
    WT2[idx] = f2b(*W);
}

// ---------------- fused SAGE layer: C = relu([agg(H)|H] @ [Wl;Wr] + b) ----------------
// 64-node x 128-col tile, 256 threads = 4 waves (2x2, wave tile 32x64).
// Phase 1: EDGE-PARALLEL gather: tile's CSR edge range split into 16 contiguous
// chunks (one per 16-lane group); accumulate f32 into LDS via ds_add_f32.
// LDS agg layout transposed-within-row: elem (row,c) at row*132 + (c&7)*16 + (c>>3)
// -> a group's 8 ds_add per edge land on 16 distinct banks (free 2-way).
// Phase 2: MFMA; agg fragments read f32 LDS, scale deg_inv, f2b at load.

__launch_bounds__(256)
__global__ void sage_layer(const unsigned short* __restrict__ H,
                           const int* __restrict__ offsets,
                           const int* __restrict__ csr_src,
                           const int* __restrict__ csr_dst,
                           const float* __restrict__ deg_inv,
                           const unsigned short* __restrict__ WT2,   // [128 n][256 k]
                           const float* __restrict__ bias,
                           unsigned short* __restrict__ Cout) {
    __shared__ float sAggF[64 * AGG_STRIDE];                 // 33792 B
    __shared__ __align__(16) unsigned short sA[64 * 32];     // 4096 B
    __shared__ __align__(16) unsigned short sW[128 * 32];    // 8192 B

    int tid  = threadIdx.x;
    int lane = tid & 63, wid = tid >> 6;
    int n0 = blockIdx.x * 64;

    // ---- zero accumulator ----
    #pragma unroll
    for (int t = 0; t < (64 * AGG_STRIDE) / 256; ++t)
        sAggF[tid + t * 256] = 0.f;
    __syncthreads();

    // ---- phase 1: edge-parallel gather-accumulate ----
    {
        int g   = tid >> 4;      // 16 groups
        int l16 = tid & 15;
        int e0 = offsets[n0];
        int nEnd = (n0 + 64 < N_NODES) ? n0 + 64 : N_NODES;
        int e1 = offsets[nEnd];
        int range = e1 - e0;
        int jbeg = e0 + ((range * g) >> 4);
        int jend = e0 + ((range * (g + 1)) >> 4);
        #pragma unroll 2
        for (int j = jbeg; j < jend; ++j) {
            int src = csr_src[j];
            int row = csr_dst[j] - n0;
            uint4 v = *(const uint4*)(H + (size_t)src * DD + l16 * 8);
            float* rp = sAggF + row * AGG_STRIDE + l16;
            atomicAdd(rp + 0 * 16, __uint_as_float(v.x << 16));
            atomicAdd(rp + 1 * 16, __uint_as_float(v.x & 0xFFFF0000u));
            atomicAdd(rp + 2 * 16, __uint_as_float(v.y << 16));
            atomicAdd(rp + 3 * 16, __uint_as_float(v.y & 0xFFFF0000u));
            atomicAdd(rp + 4 * 16, __uint_as_float(v.z << 16));
            atomicAdd(rp + 5 * 16, __uint_as_float(v.z & 0xFFFF0000u));
            atomicAdd(rp + 6 * 16, __uint_as_float(v.w << 16));
            atomicAdd(rp + 7 * 16, __uint_as_float(v.w & 0xFFFF0000u));
        }
    }
    __syncthreads();

    // ---- phase 2: MFMA ----
    int wm = wid >> 1, wn = wid & 1;
    int l15 = lane & 15, q = lane >> 4;

    floatx4 acc[2][4];
    #pragma unroll
    for (int i = 0; i < 2; ++i)
        #pragma unroll
        for (int j = 0; j < 4; ++j)
            acc[i][j] = (floatx4){0.f, 0.f, 0.f, 0.f};

    float di[2];
    #pragma unroll
    for (int i = 0; i < 2; ++i) {
        int r = n0 + wm * 32 + i * 16 + l15;
        di[i] = deg_inv[r < N_NODES ? r : N_NODES - 1];
    }

    // staging geometry
    int rA = tid >> 2, qA = (tid & 3) ^ ((rA >> 1) & 3);
    int grA = n0 + rA; if (grA > N_NODES - 1) grA = N_NODES - 1;
    int cW1 = tid + 256;
    int rW0 = tid >> 2, qW0 = (tid & 3) ^ ((rW0 >> 1) & 3);
    int rW1 = cW1 >> 2, qW1 = (cW1 & 3) ^ ((rW1 >> 1) & 3);

    #pragma unroll
    for (int half = 0; half < 2; ++half) {
        #pragma unroll
        for (int kk = 0; kk < 4; ++kk) {
            int k2 = half * 128 + kk * 32;
            if (half)
                ldsdma16(H + (size_t)grA * DD + kk * 32 + qA * 8, sA + tid * 8);
            ldsdma16(WT2 + (size_t)rW0 * 256 + k2 + qW0 * 8, sW + tid * 8);
            ldsdma16(WT2 + (size_t)rW1 * 256 + k2 + qW1 * 8, sW + cW1 * 8);
            __syncthreads();

            bf16x8 aF[2], bF[4];
            #pragma unroll
            for (int i = 0; i < 2; ++i) {
                int row = wm * 32 + i * 16 + l15;
                if (half == 0) {
                    // elem (row, c): c = kk*32 + q*8 + e  -> addr row*132 + e*16 + (kk*4+q)
                    const float* rp = sAggF + row * AGG_STRIDE + kk * 4 + q;
                    float d = di[i];
                    bf16x8 t;
                    #pragma unroll
                    for (int e = 0; e < 8; ++e)
                        t[e] = (short)f2b(rp[e * 16] * d);
                    aF[i] = t;
                } else {
                    int ca = row * 4 + (q ^ ((row >> 1) & 3));
                    aF[i] = *(const bf16x8*)(sA + ca * 8);
                }
            }
            #pragma unroll
            for (int j = 0; j < 4; ++j) {
                int nn = wn * 64 + j * 16 + l15;
                int cb = nn * 4 + (q ^ ((nn >> 1) & 3));
                bF[j] = *(const bf16x8*)(sW + cb * 8);
            }
            #pragma unroll
            for (int i = 0; i < 2; ++i)
                #pragma unroll
                for (int j = 0; j < 4; ++j)
                    acc[i][j] = __builtin_amdgcn_mfma_f32_16x16x32_bf16(aF[i], bF[j], acc[i][j], 0, 0, 0);
            __syncthreads();
        }
    }

    // ---- epilogue: bias + relu + bf16 store ----
    float bcol[4];
    #pragma unroll
    for (int j = 0; j < 4; ++j) bcol[j] = bias[wn * 64 + j * 16 + l15];
    #pragma unroll
    for (int i = 0; i < 2; ++i) {
        #pragma unroll
        for (int r = 0; r < 4; ++r) {
            int row = n0 + wm * 32 + i * 16 + q * 4 + r;
            if (row < N_NODES) {
                #pragma unroll
                for (int j = 0; j < 4; ++j) {
                    int col = wn * 64 + j * 16 + l15;
                    float v = acc[i][j][r] + bcol[j];
                    Cout[(size_t)row * DD + col] = f2b(fmaxf(v, 0.f));
                }
            }
        }
    }
}

// ---------------- final FC: out = h @ fc_W + fc_b ----------------

__global__ void fc_kernel(const unsigned short* __restrict__ h, const float* __restrict__ fcW,
                          const float* __restrict__ fcb, float* __restrict__ out) {
    int n = blockIdx.x * blockDim.x + threadIdx.x;
    if (n >= N_NODES) return;
    const unsigned* hr = (const unsigned*)(h + (size_t)n * DD);
    float s0 = fcb[0], s1 = fcb[1];
    #pragma unroll 8
    for (int k = 0; k < 64; ++k) {
        unsigned v = hr[k];
        float h0 = __uint_as_float(v << 16);
        float h1 = __uint_as_float(v & 0xFFFF0000u);
        s0 += h0 * fcW[(2 * k) * 2]     + h1 * fcW[(2 * k + 1) * 2];
        s1 += h0 * fcW[(2 * k) * 2 + 1] + h1 * fcW[(2 * k + 1) * 2 + 1];
    }
    out[n * 2] = s0; out[n * 2 + 1] = s1;
}

// ---------------- launch ----------------

extern "C" void kernel_launch(void* const* d_in, const int* in_sizes, int n_in,
                              void* d_out, int out_size, void* d_ws, size_t ws_size,
                              hipStream_t stream) {
    const float* x    = (const float*)d_in[0];
    const int*   ei   = (const int*)d_in[1];
    const float* Wl   = (const float*)d_in[2];
    const float* Wr   = (const float*)d_in[3];
    const float* bl   = (const float*)d_in[4];
    const float* fcW  = (const float*)d_in[5];
    const float* fcb  = (const float*)d_in[6];
    float* out = (float*)d_out;

    const int* srcIdx = ei;
    const int* dstIdx = ei + N_EDGES;

    char* ws = (char*)d_ws;
    size_t off = 0;
    auto bump = [&](size_t bytes) { char* p = ws + off; off = (off + bytes + 255) & ~(size_t)255; return p; };
    int*   deg     = (int*)  bump(N_NODES * 4);
    int*   cursor  = (int*)  bump(N_NODES * 4);
    int*   offsets = (int*)  bump((N_NODES + 1) * 4);
    int*   bsum    = (int*)  bump(SCAN_BLOCKS * 4);
    float* deg_inv = (float*)bump(N_NODES * 4);
    int*   csr     = (int*)  bump(N_EDGES * 4);
    int*   csrd    = (int*)  bump(N_EDGES * 4);
    unsigned short* hx   = (unsigned short*)bump((size_t)N_NODES * DD * 2);
    unsigned short* hb0  = (unsigned short*)bump((size_t)N_NODES * DD * 2);
    unsigned short* hb1  = (unsigned short*)bump((size_t)N_NODES * DD * 2);
    unsigned short* WT2  = (unsigned short*)bump((size_t)N_LAYERS * 128 * 256 * 2);
    (void)ws_size;

    zero_counts<<<(N_NODES + 255) / 256, 256, 0, stream>>>(deg, cursor);
    count_deg<<<(N_EDGES + 255) / 256, 256, 0, stream>>>(dstIdx, deg);
    block_sums<<<SCAN_BLOCKS, 256, 0, stream>>>(deg, bsum);
    scan_bsums<<<1, 256, 0, stream>>>(bsum, offsets);
    write_offsets<<<SCAN_BLOCKS, 256, 0, stream>>>(deg, bsum, offsets, deg_inv);
    fill_csr<<<(N_EDGES + 255) / 256, 256, 0, stream>>>(srcIdx, dstIdx, offsets, cursor, csr, csrd);
    x_to_bf16<<<(N_NODES * DD / 4 + 255) / 256, 256, 0, stream>>>(x, hx);
    prep_weights<<<(N_LAYERS * 128 * 256 + 255) / 256, 256, 0, stream>>>(Wl, Wr, WT2);

    const unsigned short* hin = hx;
    unsigned short* hbuf[2] = { hb0, hb1 };
    for (int l = 0; l < N_LAYERS; ++l) {
        unsigned short* hout = hbuf[l & 1];
        sage_layer<<<(N_NODES + 63) / 64, 256, 0, stream>>>(
            hin, offsets, csr, csrd, deg_inv, WT2 + (size_t)l * 128 * 256, bl + (size_t)l * DD, hout);
        hin = hout;
    }
    fc_kernel<<<(N_NODES + 255) / 256, 256, 0, stream>>>(hin, fcW, fcb, out);
}

// Round 6
// 502.792 us; speedup vs baseline: 6.5007x; 6.5007x over previous
//
#include <hip/hip_runtime.h>
#include <hip/hip_bf16.h>

#define N_NODES 50000
#define N_EDGES 600000
#define DD 128
#define N_LAYERS 6
#define SCAN_BLOCKS 196   // ceil(50000/256)

typedef __attribute__((ext_vector_type(8))) short bf16x8;
typedef __attribute__((ext_vector_type(4))) float floatx4;

__device__ __forceinline__ void ldsdma16(const void* g, void* l) {
    __builtin_amdgcn_global_load_lds(
        (const __attribute__((address_space(1))) char*)g,
        (__attribute__((address_space(3))) char*)l, 16, 0, 0);
}

__device__ __forceinline__ unsigned short f2b(float f) {
    unsigned u = __float_as_uint(f);
    unsigned r = (u + 0x7FFFu + ((u >> 16) & 1u)) >> 16;
    return (unsigned short)r;
}

// ---------------- CSR build ----------------

__global__ void zero_counts(int* __restrict__ deg, int* __restrict__ cursor) {
    int i = blockIdx.x * blockDim.x + threadIdx.x;
    if (i < N_NODES) { deg[i] = 0; cursor[i] = 0; }
}

__global__ void count_deg(const int* __restrict__ dst, int* __restrict__ deg) {
    int e = blockIdx.x * blockDim.x + threadIdx.x;
    if (e < N_EDGES) atomicAdd(&deg[dst[e]], 1);
}

__global__ void block_sums(const int* __restrict__ deg, int* __restrict__ bsum) {
    __shared__ int s[256];
    int tid = threadIdx.x;
    int i = blockIdx.x * 256 + tid;
    int v = (i < N_NODES) ? deg[i] : 0;
    s[tid] = v;
    __syncthreads();
    #pragma unroll
    for (int off = 128; off > 0; off >>= 1) {
        if (tid < off) s[tid] += s[tid + off];
        __syncthreads();
    }
    if (tid == 0) bsum[blockIdx.x] = s[0];
}

__global__ void scan_bsums(int* __restrict__ bsum, int* __restrict__ offsets) {
    __shared__ int s[256];
    int tid = threadIdx.x;
    int v = (tid < SCAN_BLOCKS) ? bsum[tid] : 0;
    s[tid] = v;
    __syncthreads();
    for (int off = 1; off < 256; off <<= 1) {
        int t = (tid >= off) ? s[tid - off] : 0;
        __syncthreads();
        s[tid] += t;
        __syncthreads();
    }
    if (tid < SCAN_BLOCKS) bsum[tid] = s[tid] - v;   // exclusive
    if (tid == 0) offsets[N_NODES] = N_EDGES;
}

__global__ void write_offsets(const int* __restrict__ deg, const int* __restrict__ bsum,
                              int* __restrict__ offsets, float* __restrict__ deg_inv) {
    __shared__ int s[256];
    int tid = threadIdx.x;
    int i = blockIdx.x * 256 + tid;
    int v = (i < N_NODES) ? deg[i] : 0;
    s[tid] = v;
    __syncthreads();
    for (int off = 1; off < 256; off <<= 1) {
        int t = (tid >= off) ? s[tid - off] : 0;
        __syncthreads();
        s[tid] += t;
        __syncthreads();
    }
    if (i < N_NODES) {
        offsets[i] = bsum[blockIdx.x] + s[tid] - v;
        deg_inv[i] = 1.0f / (float)(v > 1 ? v : 1);
    }
}

__global__ void fill_csr(const int* __restrict__ src, const int* __restrict__ dst,
                         const int* __restrict__ offsets, int* __restrict__ cursor,
                         int* __restrict__ csr_src) {
    int e = blockIdx.x * blockDim.x + threadIdx.x;
    if (e < N_EDGES) {
        int d = dst[e];
        int p = atomicAdd(&cursor[d], 1);
        csr_src[offsets[d] + p] = src[e];
    }
}

// ---------------- dtype prep ----------------

__global__ void x_to_bf16(const float* __restrict__ x, unsigned short* __restrict__ hx) {
    int idx = blockIdx.x * blockDim.x + threadIdx.x;
    int b = idx * 4;
    float4 v = *(const float4*)(x + b);
    ushort4 o;
    o.x = f2b(v.x); o.y = f2b(v.y); o.z = f2b(v.z); o.w = f2b(v.w);
    *(ushort4*)(hx + b) = o;
}

// WT2[l][n][k2]: k2<128 -> Wl[l][k2][n], else Wr[l][k2-128][n]   (bf16)
__global__ void prep_weights(const float* __restrict__ Wl, const float* __restrict__ Wr,
                             unsigned short* __restrict__ WT2) {
    int idx = blockIdx.x * blockDim.x + threadIdx.x;  // 6*128*256
    int l   = idx >> 15;
    int rem = idx & 32767;
    int n   = rem >> 8;
    int k2  = rem & 255;
    const float* W = (k2 < 128 ? Wl : Wr) + (size_t)l * DD * DD + (size_t)(k2 & 127) * DD + n;
    WT2[idx] = f2b(*W);
}

// ---------------- fused SAGE layer: C = relu([agg(H)|H] @ [Wl;Wr] + b) ----------------
// 64-node x 128-col tile, 256 threads = 4 waves.
// Phase 1: each wave aggregates its 16 rows; per node, 4 edge slots in flight
// (grp = lane>>4), xor-shuffle reduce, plain LDS store (no atomics).
// Phase 2: MFMA (R4-verified); agg half reads sAgg, h half staged via ldsdma.

__launch_bounds__(256)
__global__ void sage_layer(const unsigned short* __restrict__ H,
                           const int* __restrict__ offsets,
                           const int* __restrict__ csr_src,
                           const float* __restrict__ deg_inv,
                           const unsigned short* __restrict__ WT2,   // [128 n][256 k]
                           const float* __restrict__ bias,
                           unsigned short* __restrict__ Cout) {
    __shared__ __align__(16) unsigned short sAgg[64][136];  // 17408 B
    __shared__ __align__(16) unsigned short sA[64 * 32];    // 4096 B
    __shared__ __align__(16) unsigned short sW[128 * 32];   // 8192 B

    int tid  = threadIdx.x;
    int lane = tid & 63, wid = tid >> 6;
    int n0 = blockIdx.x * 64;
    int grp = lane >> 4;     // edge slot 0..3
    int l16 = lane & 15;     // 16B feature chunk

    // ---- phase 1: wave-per-node gather-mean, 4 edges in flight ----
    for (int r = 0; r < 16; ++r) {
        int lrow = wid * 16 + r;
        int node = n0 + lrow;
        int nc = node < N_NODES ? node : N_NODES - 1;
        int s = offsets[nc], e = offsets[nc + 1];
        float a0=0,a1=0,a2=0,a3=0,a4=0,a5=0,a6=0,a7=0;
        for (int j = s + grp; j < e; j += 4) {
            int src = csr_src[j];
            uint4 v = *(const uint4*)(H + (size_t)src * DD + l16 * 8);
            a0 += __uint_as_float(v.x << 16); a1 += __uint_as_float(v.x & 0xFFFF0000u);
            a2 += __uint_as_float(v.y << 16); a3 += __uint_as_float(v.y & 0xFFFF0000u);
            a4 += __uint_as_float(v.z << 16); a5 += __uint_as_float(v.z & 0xFFFF0000u);
            a6 += __uint_as_float(v.w << 16); a7 += __uint_as_float(v.w & 0xFFFF0000u);
        }
        a0 += __shfl_xor(a0, 16, 64); a1 += __shfl_xor(a1, 16, 64);
        a2 += __shfl_xor(a2, 16, 64); a3 += __shfl_xor(a3, 16, 64);
        a4 += __shfl_xor(a4, 16, 64); a5 += __shfl_xor(a5, 16, 64);
        a6 += __shfl_xor(a6, 16, 64); a7 += __shfl_xor(a7, 16, 64);
        a0 += __shfl_xor(a0, 32, 64); a1 += __shfl_xor(a1, 32, 64);
        a2 += __shfl_xor(a2, 32, 64); a3 += __shfl_xor(a3, 32, 64);
        a4 += __shfl_xor(a4, 32, 64); a5 += __shfl_xor(a5, 32, 64);
        a6 += __shfl_xor(a6, 32, 64); a7 += __shfl_xor(a7, 32, 64);
        if (grp == 0) {
            float di = deg_inv[nc];
            uint4 o;
            o.x = (unsigned)f2b(a0 * di) | ((unsigned)f2b(a1 * di) << 16);
            o.y = (unsigned)f2b(a2 * di) | ((unsigned)f2b(a3 * di) << 16);
            o.z = (unsigned)f2b(a4 * di) | ((unsigned)f2b(a5 * di) << 16);
            o.w = (unsigned)f2b(a6 * di) | ((unsigned)f2b(a7 * di) << 16);
            *(uint4*)&sAgg[lrow][l16 * 8] = o;
        }
    }
    __syncthreads();

    // ---- phase 2: MFMA ----
    int wm = wid >> 1, wn = wid & 1;
    int l15 = lane & 15, q = lane >> 4;

    floatx4 acc[2][4];
    #pragma unroll
    for (int i = 0; i < 2; ++i)
        #pragma unroll
        for (int j = 0; j < 4; ++j)
            acc[i][j] = (floatx4){0.f, 0.f, 0.f, 0.f};

    // staging geometry
    int rA = tid >> 2, qA = (tid & 3) ^ ((rA >> 1) & 3);
    int grA = n0 + rA; if (grA > N_NODES - 1) grA = N_NODES - 1;
    int cW1 = tid + 256;
    int rW0 = tid >> 2, qW0 = (tid & 3) ^ ((rW0 >> 1) & 3);
    int rW1 = cW1 >> 2, qW1 = (cW1 & 3) ^ ((rW1 >> 1) & 3);

    #pragma unroll
    for (int half = 0; half < 2; ++half) {
        #pragma unroll
        for (int kk = 0; kk < 4; ++kk) {
            int k2 = half * 128 + kk * 32;
            if (half)
                ldsdma16(H + (size_t)grA * DD + kk * 32 + qA * 8, sA + tid * 8);
            ldsdma16(WT2 + (size_t)rW0 * 256 + k2 + qW0 * 8, sW + tid * 8);
            ldsdma16(WT2 + (size_t)rW1 * 256 + k2 + qW1 * 8, sW + cW1 * 8);
            __syncthreads();

            bf16x8 aF[2], bF[4];
            #pragma unroll
            for (int i = 0; i < 2; ++i) {
                int row = wm * 32 + i * 16 + l15;
                if (half == 0) {
                    aF[i] = *(const bf16x8*)&sAgg[row][kk * 32 + q * 8];
                } else {
                    int ca = row * 4 + (q ^ ((row >> 1) & 3));
                    aF[i] = *(const bf16x8*)(sA + ca * 8);
                }
            }
            #pragma unroll
            for (int j = 0; j < 4; ++j) {
                int nn = wn * 64 + j * 16 + l15;
                int cb = nn * 4 + (q ^ ((nn >> 1) & 3));
                bF[j] = *(const bf16x8*)(sW + cb * 8);
            }
            #pragma unroll
            for (int i = 0; i < 2; ++i)
                #pragma unroll
                for (int j = 0; j < 4; ++j)
                    acc[i][j] = __builtin_amdgcn_mfma_f32_16x16x32_bf16(aF[i], bF[j], acc[i][j], 0, 0, 0);
            __syncthreads();
        }
    }

    // ---- epilogue: bias + relu + bf16 store ----
    float bcol[4];
    #pragma unroll
    for (int j = 0; j < 4; ++j) bcol[j] = bias[wn * 64 + j * 16 + l15];
    #pragma unroll
    for (int i = 0; i < 2; ++i) {
        #pragma unroll
        for (int r = 0; r < 4; ++r) {
            int row = n0 + wm * 32 + i * 16 + q * 4 + r;
            if (row < N_NODES) {
                #pragma unroll
                for (int j = 0; j < 4; ++j) {
                    int col = wn * 64 + j * 16 + l15;
                    float v = acc[i][j][r] + bcol[j];
                    Cout[(size_t)row * DD + col] = f2b(fmaxf(v, 0.f));
                }
            }
        }
    }
}

// ---------------- final FC: out = h @ fc_W + fc_b ----------------

__global__ void fc_kernel(const unsigned short* __restrict__ h, const float* __restrict__ fcW,
                          const float* __restrict__ fcb, float* __restrict__ out) {
    int n = blockIdx.x * blockDim.x + threadIdx.x;
    if (n >= N_NODES) return;
    const unsigned* hr = (const unsigned*)(h + (size_t)n * DD);
    float s0 = fcb[0], s1 = fcb[1];
    #pragma unroll 8
    for (int k = 0; k < 64; ++k) {
        unsigned v = hr[k];
        float h0 = __uint_as_float(v << 16);
        float h1 = __uint_as_float(v & 0xFFFF0000u);
        s0 += h0 * fcW[(2 * k) * 2]     + h1 * fcW[(2 * k + 1) * 2];
        s1 += h0 * fcW[(2 * k) * 2 + 1] + h1 * fcW[(2 * k + 1) * 2 + 1];
    }
    out[n * 2] = s0; out[n * 2 + 1] = s1;
}

// ---------------- launch ----------------

extern "C" void kernel_launch(void* const* d_in, const int* in_sizes, int n_in,
                              void* d_out, int out_size, void* d_ws, size_t ws_size,
                              hipStream_t stream) {
    const float* x    = (const float*)d_in[0];
    const int*   ei   = (const int*)d_in[1];
    const float* Wl   = (const float*)d_in[2];
    const float* Wr   = (const float*)d_in[3];
    const float* bl   = (const float*)d_in[4];
    const float* fcW  = (const float*)d_in[5];
    const float* fcb  = (const float*)d_in[6];
    float* out = (float*)d_out;

    const int* srcIdx = ei;
    const int* dstIdx = ei + N_EDGES;

    char* ws = (char*)d_ws;
    size_t off = 0;
    auto bump = [&](size_t bytes) { char* p = ws + off; off = (off + bytes + 255) & ~(size_t)255; return p; };
    int*   deg     = (int*)  bump(N_NODES * 4);
    int*   cursor  = (int*)  bump(N_NODES * 4);
    int*   offsets = (int*)  bump((N_NODES + 1) * 4);
    int*   bsum    = (int*)  bump(SCAN_BLOCKS * 4);
    float* deg_inv = (float*)bump(N_NODES * 4);
    int*   csr     = (int*)  bump(N_EDGES * 4);
    unsigned short* hx   = (unsigned short*)bump((size_t)N_NODES * DD * 2);
    unsigned short* hb0  = (unsigned short*)bump((size_t)N_NODES * DD * 2);
    unsigned short* hb1  = (unsigned short*)bump((size_t)N_NODES * DD * 2);
    unsigned short* WT2  = (unsigned short*)bump((size_t)N_LAYERS * 128 * 256 * 2);
    (void)ws_size;

    zero_counts<<<(N_NODES + 255) / 256, 256, 0, stream>>>(deg, cursor);
    count_deg<<<(N_EDGES + 255) / 256, 256, 0, stream>>>(dstIdx, deg);
    block_sums<<<SCAN_BLOCKS, 256, 0, stream>>>(deg, bsum);
    scan_bsums<<<1, 256, 0, stream>>>(bsum, offsets);
    write_offsets<<<SCAN_BLOCKS, 256, 0, stream>>>(deg, bsum, offsets, deg_inv);
    fill_csr<<<(N_EDGES + 255) / 256, 256, 0, stream>>>(srcIdx, dstIdx, offsets, cursor, csr);
    x_to_bf16<<<(N_NODES * DD / 4 + 255) / 256, 256, 0, stream>>>(x, hx);
    prep_weights<<<(N_LAYERS * 128 * 256 + 255) / 256, 256, 0, stream>>>(Wl, Wr, WT2);

    const unsigned short* hin = hx;
    unsigned short* hbuf[2] = { hb0, hb1 };
    for (int l = 0; l < N_LAYERS; ++l) {
        unsigned short* hout = hbuf[l & 1];
        sage_layer<<<(N_NODES + 63) / 64, 256, 0, stream>>>(
            hin, offsets, csr, deg_inv, WT2 + (size_t)l * 128 * 256, bl + (size_t)l * DD, hout);
        hin = hout;
    }
    fc_kernel<<<(N_NODES + 255) / 256, 256, 0, stream>>>(hin, fcW, fcb, out);
}

// Round 7
// 401.716 us; speedup vs baseline: 8.1364x; 1.2516x over previous
//
#include <hip/hip_runtime.h>
#include <hip/hip_bf16.h>

#define N_NODES 50000
#define N_EDGES 600000
#define DD 128
#define N_LAYERS 6
#define SCAN_BLOCKS 196   // ceil(50000/256)
#define N_CHUNKS 3125     // 50000 / 16

typedef __attribute__((ext_vector_type(8))) short bf16x8;
typedef __attribute__((ext_vector_type(4))) float floatx4;

__device__ __forceinline__ void ldsdma16(const void* g, void* l) {
    __builtin_amdgcn_global_load_lds(
        (const __attribute__((address_space(1))) char*)g,
        (__attribute__((address_space(3))) char*)l, 16, 0, 0);
}

__device__ __forceinline__ unsigned short f2b(float f) {
    unsigned u = __float_as_uint(f);
    unsigned r = (u + 0x7FFFu + ((u >> 16) & 1u)) >> 16;
    return (unsigned short)r;
}

// ---------------- CSR build ----------------

__global__ void zero_counts(int* __restrict__ deg, int* __restrict__ cursor) {
    int i = blockIdx.x * blockDim.x + threadIdx.x;
    if (i < N_NODES) { deg[i] = 0; cursor[i] = 0; }
}

__global__ void count_deg(const int* __restrict__ dst, int* __restrict__ deg) {
    int e = blockIdx.x * blockDim.x + threadIdx.x;
    if (e < N_EDGES) atomicAdd(&deg[dst[e]], 1);
}

__global__ void block_sums(const int* __restrict__ deg, int* __restrict__ bsum) {
    __shared__ int s[256];
    int tid = threadIdx.x;
    int i = blockIdx.x * 256 + tid;
    int v = (i < N_NODES) ? deg[i] : 0;
    s[tid] = v;
    __syncthreads();
    #pragma unroll
    for (int off = 128; off > 0; off >>= 1) {
        if (tid < off) s[tid] += s[tid + off];
        __syncthreads();
    }
    if (tid == 0) bsum[blockIdx.x] = s[0];
}

__global__ void scan_bsums(int* __restrict__ bsum, int* __restrict__ offsets) {
    __shared__ int s[256];
    int tid = threadIdx.x;
    int v = (tid < SCAN_BLOCKS) ? bsum[tid] : 0;
    s[tid] = v;
    __syncthreads();
    for (int off = 1; off < 256; off <<= 1) {
        int t = (tid >= off) ? s[tid - off] : 0;
        __syncthreads();
        s[tid] += t;
        __syncthreads();
    }
    if (tid < SCAN_BLOCKS) bsum[tid] = s[tid] - v;   // exclusive
    if (tid == 0) offsets[N_NODES] = N_EDGES;
}

__global__ void write_offsets(const int* __restrict__ deg, const int* __restrict__ bsum,
                              int* __restrict__ offsets, float* __restrict__ deg_inv) {
    __shared__ int s[256];
    int tid = threadIdx.x;
    int i = blockIdx.x * 256 + tid;
    int v = (i < N_NODES) ? deg[i] : 0;
    s[tid] = v;
    __syncthreads();
    for (int off = 1; off < 256; off <<= 1) {
        int t = (tid >= off) ? s[tid - off] : 0;
        __syncthreads();
        s[tid] += t;
        __syncthreads();
    }
    if (i < N_NODES) {
        offsets[i] = bsum[blockIdx.x] + s[tid] - v;
        deg_inv[i] = 1.0f / (float)(v > 1 ? v : 1);
    }
}

__global__ void fill_csr(const int* __restrict__ src, const int* __restrict__ dst,
                         const int* __restrict__ offsets, int* __restrict__ cursor,
                         int* __restrict__ csr_src) {
    int e = blockIdx.x * blockDim.x + threadIdx.x;
    if (e < N_EDGES) {
        int d = dst[e];
        int p = atomicAdd(&cursor[d], 1);
        csr_src[offsets[d] + p] = src[e];
    }
}

// ---------------- dtype prep ----------------

__global__ void x_to_bf16(const float* __restrict__ x, unsigned short* __restrict__ hx) {
    int idx = blockIdx.x * blockDim.x + threadIdx.x;
    int b = idx * 4;
    float4 v = *(const float4*)(x + b);
    ushort4 o;
    o.x = f2b(v.x); o.y = f2b(v.y); o.z = f2b(v.z); o.w = f2b(v.w);
    *(ushort4*)(hx + b) = o;
}

// WT2[l][n][k2]: k2<128 -> Wl[l][k2][n], else Wr[l][k2-128][n]   (bf16)
__global__ void prep_weights(const float* __restrict__ Wl, const float* __restrict__ Wr,
                             unsigned short* __restrict__ WT2) {
    int idx = blockIdx.x * blockDim.x + threadIdx.x;  // 6*128*256
    int l   = idx >> 15;
    int rem = idx & 32767;
    int n   = rem >> 8;
    int k2  = rem & 255;
    const float* W = (k2 < 128 ? Wl : Wr) + (size_t)l * DD * DD + (size_t)(k2 & 127) * DD + n;
    WT2[idx] = f2b(*W);
}

// ---------------- mean aggregation (wave per node, 4 edges in flight) ----------------

__global__ void aggregate(const unsigned short* __restrict__ hin, const int* __restrict__ offsets,
                          const int* __restrict__ csr_src, const float* __restrict__ deg_inv,
                          unsigned short* __restrict__ agg) {
    int wid  = threadIdx.x >> 6;
    int lane = threadIdx.x & 63;
    int grp  = lane >> 4;      // edge slot
    int l16  = lane & 15;      // 16B feature chunk
    int node = blockIdx.x * 4 + wid;
    if (node >= N_NODES) return;
    int s = offsets[node], e = offsets[node + 1];

    float a0=0,a1=0,a2=0,a3=0,a4=0,a5=0,a6=0,a7=0;
    for (int j = s + grp; j < e; j += 4) {
        int src = csr_src[j];
        uint4 v = *(const uint4*)(hin + (size_t)src * DD + l16 * 8);
        a0 += __uint_as_float(v.x << 16); a1 += __uint_as_float(v.x & 0xFFFF0000u);
        a2 += __uint_as_float(v.y << 16); a3 += __uint_as_float(v.y & 0xFFFF0000u);
        a4 += __uint_as_float(v.z << 16); a5 += __uint_as_float(v.z & 0xFFFF0000u);
        a6 += __uint_as_float(v.w << 16); a7 += __uint_as_float(v.w & 0xFFFF0000u);
    }
    a0 += __shfl_xor(a0, 16, 64); a1 += __shfl_xor(a1, 16, 64);
    a2 += __shfl_xor(a2, 16, 64); a3 += __shfl_xor(a3, 16, 64);
    a4 += __shfl_xor(a4, 16, 64); a5 += __shfl_xor(a5, 16, 64);
    a6 += __shfl_xor(a6, 16, 64); a7 += __shfl_xor(a7, 16, 64);
    a0 += __shfl_xor(a0, 32, 64); a1 += __shfl_xor(a1, 32, 64);
    a2 += __shfl_xor(a2, 32, 64); a3 += __shfl_xor(a3, 32, 64);
    a4 += __shfl_xor(a4, 32, 64); a5 += __shfl_xor(a5, 32, 64);
    a6 += __shfl_xor(a6, 32, 64); a7 += __shfl_xor(a7, 32, 64);

    if (grp == 0) {
        float di = deg_inv[node];
        uint4 o;
        o.x = (unsigned)f2b(a0 * di) | ((unsigned)f2b(a1 * di) << 16);
        o.y = (unsigned)f2b(a2 * di) | ((unsigned)f2b(a3 * di) << 16);
        o.z = (unsigned)f2b(a4 * di) | ((unsigned)f2b(a5 * di) << 16);
        o.w = (unsigned)f2b(a6 * di) | ((unsigned)f2b(a7 * di) << 16);
        *(uint4*)(agg + (size_t)node * DD + l16 * 8) = o;
    }
}

// ---------------- resident-W streaming GEMM: C = relu([Agg|H] @ W2 + b) ----------------
// 256 blocks x 512 threads (8 waves, 1 block/CU). W2 (128x256 bf16, 64 KB) lives
// in LDS for the whole kernel (XOR-swizzled). Each wave independently grid-strides
// over 16-row chunks: 8x ldsdma16 (global-side XOR swizzle), waitcnt, 64 MFMA,
// epilogue. No __syncthreads in the loop.

__launch_bounds__(512, 2)
__global__ void gemm_resW(const unsigned short* __restrict__ Agg,
                          const unsigned short* __restrict__ H,
                          const unsigned short* __restrict__ WT2,   // [128 n][256 k]
                          const float* __restrict__ bias,
                          unsigned short* __restrict__ Cout) {
    __shared__ __align__(16) unsigned short sW[128 * 256];     // 64 KB
    __shared__ __align__(16) unsigned short sA[8][4096];       // 8 KB per wave

    int tid  = threadIdx.x;
    int wid  = tid >> 6, lane = tid & 63;
    int l15  = lane & 15, q = lane >> 4;

    // ---- fill sW (swizzled: chunk c of col stored at col*32 + (c ^ (col&7))) ----
    for (int t = tid; t < 4096; t += 512) {
        int col = t >> 5, c = t & 31;
        uint4 v = *(const uint4*)(WT2 + (size_t)col * 256 + c * 8);
        *(uint4*)(sW + ((size_t)col * 32 + (c ^ (col & 7))) * 8) = v;
    }
    __syncthreads();

    float bcol[8];
    #pragma unroll
    for (int j = 0; j < 8; ++j) bcol[j] = bias[j * 16 + l15];

    unsigned short* myA = &sA[wid][0];

    for (int chunk = blockIdx.x * 8 + wid; chunk < N_CHUNKS; chunk += 2048) {
        int row0 = chunk * 16;
        // ---- stage 16 rows of [agg(16 chunks) | h(16 chunks)] ----
        // dma i: lane l -> row r = i*4 + q, fetch global chunk (l15 ^ (r&7)),
        // LDS dest = region + i*1024 + lane*16  (==> pos r*16 + l15)
        #pragma unroll
        for (int i = 0; i < 4; ++i) {
            int r  = i * 4 + q;
            int cg = l15 ^ (r & 7);
            ldsdma16(Agg + (size_t)(row0 + r) * DD + cg * 8, myA + (size_t)i * 512 + lane * 8);
        }
        #pragma unroll
        for (int i = 0; i < 4; ++i) {
            int r  = i * 4 + q;
            int cg = l15 ^ (r & 7);
            ldsdma16(H + (size_t)(row0 + r) * DD + cg * 8, myA + 2048 + (size_t)i * 512 + lane * 8);
        }
        __builtin_amdgcn_s_waitcnt(0);   // drain vm before reading own sA slice

        // ---- compute: 8 k-steps x 8 col-tiles ----
        floatx4 acc[8];
        #pragma unroll
        for (int j = 0; j < 8; ++j) acc[j] = (floatx4){0.f, 0.f, 0.f, 0.f};

        #pragma unroll
        for (int s = 0; s < 8; ++s) {
            int cglob = s * 4 + q;               // global k-chunk 0..31
            int reg   = cglob >> 4;              // 0: agg, 1: h
            int cin   = cglob & 15;
            bf16x8 aF = *(const bf16x8*)(myA + (size_t)reg * 2048 +
                                         ((size_t)l15 * 16 + (cin ^ (l15 & 7))) * 8);
            #pragma unroll
            for (int j = 0; j < 8; ++j) {
                int col = j * 16 + l15;
                bf16x8 bF = *(const bf16x8*)(sW + ((size_t)col * 32 + (cglob ^ (col & 7))) * 8);
                acc[j] = __builtin_amdgcn_mfma_f32_16x16x32_bf16(aF, bF, acc[j], 0, 0, 0);
            }
        }

        // ---- epilogue: bias + relu + bf16 store ----
        #pragma unroll
        for (int r = 0; r < 4; ++r) {
            int row = row0 + q * 4 + r;
            #pragma unroll
            for (int j = 0; j < 8; ++j) {
                float v = acc[j][r] + bcol[j];
                Cout[(size_t)row * DD + j * 16 + l15] = f2b(fmaxf(v, 0.f));
            }
        }
    }
}

// ---------------- final FC: out = h @ fc_W + fc_b ----------------

__global__ void fc_kernel(const unsigned short* __restrict__ h, const float* __restrict__ fcW,
                          const float* __restrict__ fcb, float* __restrict__ out) {
    int n = blockIdx.x * blockDim.x + threadIdx.x;
    if (n >= N_NODES) return;
    const unsigned* hr = (const unsigned*)(h + (size_t)n * DD);
    float s0 = fcb[0], s1 = fcb[1];
    #pragma unroll 8
    for (int k = 0; k < 64; ++k) {
        unsigned v = hr[k];
        float h0 = __uint_as_float(v << 16);
        float h1 = __uint_as_float(v & 0xFFFF0000u);
        s0 += h0 * fcW[(2 * k) * 2]     + h1 * fcW[(2 * k + 1) * 2];
        s1 += h0 * fcW[(2 * k) * 2 + 1] + h1 * fcW[(2 * k + 1) * 2 + 1];
    }
    out[n * 2] = s0; out[n * 2 + 1] = s1;
}

// ---------------- launch ----------------

extern "C" void kernel_launch(void* const* d_in, const int* in_sizes, int n_in,
                              void* d_out, int out_size, void* d_ws, size_t ws_size,
                              hipStream_t stream) {
    const float* x    = (const float*)d_in[0];
    const int*   ei   = (const int*)d_in[1];
    const float* Wl   = (const float*)d_in[2];
    const float* Wr   = (const float*)d_in[3];
    const float* bl   = (const float*)d_in[4];
    const float* fcW  = (const float*)d_in[5];
    const float* fcb  = (const float*)d_in[6];
    float* out = (float*)d_out;

    const int* srcIdx = ei;
    const int* dstIdx = ei + N_EDGES;

    char* ws = (char*)d_ws;
    size_t off = 0;
    auto bump = [&](size_t bytes) { char* p = ws + off; off = (off + bytes + 255) & ~(size_t)255; return p; };
    int*   deg     = (int*)  bump(N_NODES * 4);
    int*   cursor  = (int*)  bump(N_NODES * 4);
    int*   offsets = (int*)  bump((N_NODES + 1) * 4);
    int*   bsum    = (int*)  bump(SCAN_BLOCKS * 4);
    float* deg_inv = (float*)bump(N_NODES * 4);
    int*   csr     = (int*)  bump(N_EDGES * 4);
    unsigned short* hx   = (unsigned short*)bump((size_t)N_NODES * DD * 2);
    unsigned short* hb0  = (unsigned short*)bump((size_t)N_NODES * DD * 2);
    unsigned short* hb1  = (unsigned short*)bump((size_t)N_NODES * DD * 2);
    unsigned short* agg  = (unsigned short*)bump((size_t)N_NODES * DD * 2);
    unsigned short* WT2  = (unsigned short*)bump((size_t)N_LAYERS * 128 * 256 * 2);
    (void)ws_size;

    zero_counts<<<(N_NODES + 255) / 256, 256, 0, stream>>>(deg, cursor);
    count_deg<<<(N_EDGES + 255) / 256, 256, 0, stream>>>(dstIdx, deg);
    block_sums<<<SCAN_BLOCKS, 256, 0, stream>>>(deg, bsum);
    scan_bsums<<<1, 256, 0, stream>>>(bsum, offsets);
    write_offsets<<<SCAN_BLOCKS, 256, 0, stream>>>(deg, bsum, offsets, deg_inv);
    fill_csr<<<(N_EDGES + 255) / 256, 256, 0, stream>>>(srcIdx, dstIdx, offsets, cursor, csr);
    x_to_bf16<<<(N_NODES * DD / 4 + 255) / 256, 256, 0, stream>>>(x, hx);
    prep_weights<<<(N_LAYERS * 128 * 256 + 255) / 256, 256, 0, stream>>>(Wl, Wr, WT2);

    const unsigned short* hin = hx;
    unsigned short* hbuf[2] = { hb0, hb1 };
    for (int l = 0; l < N_LAYERS; ++l) {
        aggregate<<<(N_NODES + 3) / 4, 256, 0, stream>>>(hin, offsets, csr, deg_inv, agg);
        unsigned short* hout = hbuf[l & 1];
        gemm_resW<<<256, 512, 0, stream>>>(
            agg, hin, WT2 + (size_t)l * 128 * 256, bl + (size_t)l * DD, hout);
        hin = hout;
    }
    fc_kernel<<<(N_NODES + 255) / 256, 256, 0, stream>>>(hin, fcW, fcb, out);
}